// Round 1
// baseline (323.369 us; speedup 1.0000x reference)
//
#include <hip/hip_runtime.h>
#include <math.h>

#define NE 8      // experts
#define ND 512    // features
#define NH 2048   // hidden
#define NT 2048   // tokens = B*S

typedef __attribute__((ext_vector_type(8))) short short8;   // 8 bf16 = 4 VGPRs
typedef __attribute__((ext_vector_type(4))) float f32x4;    // MFMA accumulator

#define GLL(g, d) __builtin_amdgcn_global_load_lds( \
    (const __attribute__((address_space(1))) void*)(g), \
    (__attribute__((address_space(3))) void*)(d), 16, 0, 0)

__device__ __forceinline__ unsigned short f2bf(float x) {
    unsigned int u = __builtin_bit_cast(unsigned int, x);
    u += 0x7FFFu + ((u >> 16) & 1u);            // round-to-nearest-even
    return (unsigned short)(u >> 16);
}

__device__ __forceinline__ short8 neg8(short8 v) {
    int4 u = __builtin_bit_cast(int4, v);
    u.x ^= 0x80008000; u.y ^= 0x80008000; u.z ^= 0x80008000; u.w ^= 0x80008000;
    return __builtin_bit_cast(short8, u);
}

__device__ __forceinline__ short8 lds8(const unsigned short* p) {
    return *(const short8*)p;
}

// ---------------- gating (fp32, exact argmax semantics) ----------------
__global__ __launch_bounds__(256) void gate_kernel(
    const float* __restrict__ xr, const float* __restrict__ xi,
    const float* __restrict__ gW, const float* __restrict__ gb,
    float* __restrict__ gate_w,
    int* __restrict__ counts, int* __restrict__ tok_list)
{
    int t = blockIdx.x;
    int tid = threadIdx.x;
    const float* xrt = xr + (size_t)t * ND;
    const float* xit = xi + (size_t)t * ND;

    float acc[NE] = {0,0,0,0,0,0,0,0};
    for (int r = tid; r < 2 * ND; r += 256) {
        int d = r & (ND - 1);
        float a = xrt[d], b = xit[d];
        float v = (r < ND) ? sqrtf(a * a + b * b) : atan2f(b, a);
        const float4* g = (const float4*)(gW + (size_t)r * NE);
        float4 g0 = g[0], g1 = g[1];
        acc[0] += v * g0.x; acc[1] += v * g0.y; acc[2] += v * g0.z; acc[3] += v * g0.w;
        acc[4] += v * g1.x; acc[5] += v * g1.y; acc[6] += v * g1.z; acc[7] += v * g1.w;
    }
    #pragma unroll
    for (int e = 0; e < NE; e++) {
        for (int off = 32; off > 0; off >>= 1)
            acc[e] += __shfl_down(acc[e], off, 64);
    }
    __shared__ float part[4][NE];
    int wave = tid >> 6, lane = tid & 63;
    if (lane == 0) {
        #pragma unroll
        for (int e = 0; e < NE; e++) part[wave][e] = acc[e];
    }
    __syncthreads();
    if (tid == 0) {
        float s[NE];
        #pragma unroll
        for (int e = 0; e < NE; e++)
            s[e] = part[0][e] + part[1][e] + part[2][e] + part[3][e] + gb[e];
        int amax = 0; float m = s[0];
        #pragma unroll
        for (int e = 1; e < NE; e++) if (s[e] > m) { m = s[e]; amax = e; }
        float denom = 0.f;
        #pragma unroll
        for (int e = 0; e < NE; e++) denom += expf(s[e] - m);
        gate_w[t] = 1.0f / denom;
        int pos = atomicAdd(&counts[amax], 1);
        tok_list[amax * NT + pos] = t;
    }
}

// ---------------- x -> bf16 ----------------
__global__ __launch_bounds__(256) void convx_kernel(
    const float* __restrict__ xr, const float* __restrict__ xi,
    unsigned short* __restrict__ obr, unsigned short* __restrict__ obi)
{
    int i = blockIdx.x * 256 + threadIdx.x;
    float4 vr = ((const float4*)xr)[i];
    float4 vi = ((const float4*)xi)[i];
    ((ushort4*)obr)[i] = make_ushort4(f2bf(vr.x), f2bf(vr.y), f2bf(vr.z), f2bf(vr.w));
    ((ushort4*)obi)[i] = make_ushort4(f2bf(vi.x), f2bf(vi.y), f2bf(vi.z), f2bf(vi.w));
}

// ---------------- weight transpose + bf16: src fp32 [e][R][C] -> dst bf16 [e][C][R] ----
// writes vectorized as ushort4 (was scalar 2B stores = half-rate write path)
__global__ __launch_bounds__(256) void transw_kernel(
    const float* __restrict__ s0, unsigned short* __restrict__ d0,
    const float* __restrict__ s1, unsigned short* __restrict__ d1,
    int R, int C)
{
    __shared__ float tile[64][65];
    int e = blockIdx.z;
    int c0 = blockIdx.x * 64, r0 = blockIdx.y * 64;
    size_t off = (size_t)e * R * C;
    int tid = threadIdx.x;
    #pragma unroll
    for (int p = 0; p < 2; ++p) {
        const float* src = (p ? s1 : s0) + off;
        unsigned short* dst = (p ? d1 : d0) + off;
        if (p) __syncthreads();
        for (int i = 0; i < 16; ++i) {
            int idx = tid + i * 256;
            int r = idx >> 6, c = idx & 63;
            tile[r][c] = src[(size_t)(r0 + r) * C + c0 + c];
        }
        __syncthreads();
        #pragma unroll
        for (int i = 0; i < 4; ++i) {
            int c = i * 16 + (tid >> 4);
            int r4 = (tid & 15) * 4;
            ushort4 v = make_ushort4(f2bf(tile[r4][c]), f2bf(tile[r4 + 1][c]),
                                     f2bf(tile[r4 + 2][c]), f2bf(tile[r4 + 3][c]));
            *(ushort4*)&dst[(size_t)(c0 + c) * R + r0 + r4] = v;
        }
    }
}

// ---------------- shared GEMM machinery for moe1/moe2 ----------------
// Double-buffered LDS (8 x 8KB = 64KB), T3-minimal pipeline:
//   STAGE(next tile) -> compute(current) -> vmcnt(0)+lgkmcnt(0) -> s_barrier
// One barrier per K-step; prefetch latency hides under the 32 MFMAs.
// LDS XOR swizzle unchanged: physical k-chunk = logical ^ (row & 7), applied
// on the global-source side of GLL (LDS slot order fixed to lane order).

#define STAGE_(SA_R, SA_I, SB_R, SB_I, ko) do {  \
    GLL(gAr0 + (ko), SA_R + (w * 16) * 64);      \
    GLL(gAi0 + (ko), SA_I + (w * 16) * 64);      \
    GLL(gAr1 + (ko), SA_R + (w * 16 + 8) * 64);  \
    GLL(gAi1 + (ko), SA_I + (w * 16 + 8) * 64);  \
    GLL(gBr0 + (ko), SB_R + (w * 16) * 64);      \
    GLL(gBr1 + (ko), SB_R + (w * 16 + 8) * 64);  \
    GLL(gBi0 + (ko), SB_I + (w * 16) * 64);      \
    GLL(gBi1 + (ko), SB_I + (w * 16 + 8) * 64);  \
} while (0)

#define COMPUTE_(SA_R, SA_I, SB_R, SB_I) do {                                          \
    _Pragma("unroll")                                                                  \
    for (int ks = 0; ks < 2; ++ks) {                                                   \
        int pa = ((ks * 4 + quad) ^ (l15 & 7)) * 8;                                    \
        short8 br  = lds8(SB_R + (w * 16 + l15) * 64 + pa);                            \
        short8 bi2 = lds8(SB_I + (w * 16 + l15) * 64 + pa);                            \
        _Pragma("unroll")                                                              \
        for (int m = 0; m < 4; ++m) {                                                  \
            short8 ar  = lds8(SA_R + (m * 16 + l15) * 64 + pa);                        \
            short8 ai2 = lds8(SA_I + (m * 16 + l15) * 64 + pa);                        \
            short8 an  = neg8(ai2);                                                    \
            accr[m] = __builtin_amdgcn_mfma_f32_16x16x32_bf16(ar,  br,  accr[m], 0, 0, 0); \
            accr[m] = __builtin_amdgcn_mfma_f32_16x16x32_bf16(an,  bi2, accr[m], 0, 0, 0); \
            acci[m] = __builtin_amdgcn_mfma_f32_16x16x32_bf16(ar,  bi2, acci[m], 0, 0, 0); \
            acci[m] = __builtin_amdgcn_mfma_f32_16x16x32_bf16(ai2, br,  acci[m], 0, 0, 0); \
        }                                                                              \
    }                                                                                  \
} while (0)

#define SYNCPIPE do {                                               \
    asm volatile("s_waitcnt vmcnt(0) lgkmcnt(0)" ::: "memory");     \
    __builtin_amdgcn_s_barrier();                                   \
    __builtin_amdgcn_sched_barrier(0);                              \
} while (0)

#define MOE_LDS_DECL                                                        \
    __shared__ alignas(16) unsigned short sAr0[4096], sAi0[4096];           \
    __shared__ alignas(16) unsigned short sBr0[4096], sBi0[4096];           \
    __shared__ alignas(16) unsigned short sAr1[4096], sAi1[4096];           \
    __shared__ alignas(16) unsigned short sBr1[4096], sBi1[4096];

// ---------------- stage 1: complex D->H, pipelined MFMA + ModReLU -> h bf16 ---
__global__ __launch_bounds__(256, 2) void moe1_kernel(
    const unsigned short* __restrict__ xbr, const unsigned short* __restrict__ xbi,
    const unsigned short* __restrict__ w1tr, const unsigned short* __restrict__ w1ti,
    const float* __restrict__ b1r, const float* __restrict__ b1i,
    const float* __restrict__ mod_b,
    const int* __restrict__ counts, const int* __restrict__ tok_list,
    unsigned short* __restrict__ hr, unsigned short* __restrict__ hi)
{
    int e = blockIdx.z;
    int n = counts[e];
    int mbase = blockIdx.y * 64;
    if (mbase >= n) return;
    int n0 = blockIdx.x * 64;
    int tid = threadIdx.x;
    int w = tid >> 6, l = tid & 63;
    int l15 = l & 15, quad = l >> 4;

    MOE_LDS_DECL

    const int* tl = tok_list + e * NT;
    int swz = (((l & 7) ^ ((l >> 3) & 7)) * 8);
    int ia0 = mbase + w * 16 + (l >> 3);
    int ia1 = ia0 + 8;
    int ra0 = tl[ia0 < n ? ia0 : n - 1];
    int ra1 = tl[ia1 < n ? ia1 : n - 1];
    const unsigned short* gAr0 = xbr + (size_t)ra0 * ND + swz;
    const unsigned short* gAi0 = xbi + (size_t)ra0 * ND + swz;
    const unsigned short* gAr1 = xbr + (size_t)ra1 * ND + swz;
    const unsigned short* gAi1 = xbi + (size_t)ra1 * ND + swz;
    size_t brow = (size_t)e * NH + n0 + w * 16 + (l >> 3);
    const unsigned short* gBr0 = w1tr + brow * ND + swz;
    const unsigned short* gBr1 = w1tr + (brow + 8) * ND + swz;
    const unsigned short* gBi0 = w1ti + brow * ND + swz;
    const unsigned short* gBi1 = w1ti + (brow + 8) * ND + swz;

    f32x4 accr[4] = {}, acci[4] = {};

    STAGE_(sAr0, sAi0, sBr0, sBi0, 0);
    SYNCPIPE;
    #pragma unroll 1
    for (int kt = 0; kt < ND / 64; kt += 2) {
        if (kt + 1 < ND / 64) STAGE_(sAr1, sAi1, sBr1, sBi1, (kt + 1) * 64);
        COMPUTE_(sAr0, sAi0, sBr0, sBi0);
        SYNCPIPE;
        if (kt + 2 < ND / 64) STAGE_(sAr0, sAi0, sBr0, sBi0, (kt + 2) * 64);
        COMPUTE_(sAr1, sAi1, sBr1, sBi1);
        SYNCPIPE;
    }

    // epilogue: C/D layout col = lane&15 (N), row = quad*4 + r (M)
    int col = n0 + w * 16 + l15;
    float bre = b1r[(size_t)e * NH + col];
    float bie = b1i[(size_t)e * NH + col];
    float mbv = mod_b[(size_t)e * NH + col];
    #pragma unroll
    for (int m = 0; m < 4; ++m) {
        #pragma unroll
        for (int r = 0; r < 4; ++r) {
            int tix = m * 16 + quad * 4 + r;
            if (mbase + tix >= n) continue;
            int tok = tl[mbase + tix];
            float vr = accr[m][r] + bre;
            float vi = acci[m][r] + bie;
            float a = sqrtf(vr * vr + vi * vi + 1e-10f);
            float sc = fmaxf(a + mbv, 0.0f) / (a + 1e-10f);
            hr[(size_t)tok * NH + col] = f2bf(vr * sc);
            hi[(size_t)tok * NH + col] = f2bf(vi * sc);
        }
    }
}

// ---------------- stage 2: complex H->D, split-K=2, pipelined MFMA -> atomic out
__global__ __launch_bounds__(256, 2) void moe2_kernel(
    const unsigned short* __restrict__ hr, const unsigned short* __restrict__ hi,
    const unsigned short* __restrict__ w2tr, const unsigned short* __restrict__ w2ti,
    const float* __restrict__ b2r, const float* __restrict__ b2i,
    const int* __restrict__ counts, const int* __restrict__ tok_list,
    const float* __restrict__ gate_w,
    float* __restrict__ out)
{
    int e = blockIdx.z >> 1;
    int ksl = blockIdx.z & 1;
    int n = counts[e];
    int mbase = blockIdx.y * 64;
    if (mbase >= n) return;
    int n0 = blockIdx.x * 64;
    int kbase = ksl * (NH / 2);
    int tid = threadIdx.x;
    int w = tid >> 6, l = tid & 63;
    int l15 = l & 15, quad = l >> 4;

    MOE_LDS_DECL

    const int* tl = tok_list + e * NT;
    int swz = (((l & 7) ^ ((l >> 3) & 7)) * 8);
    int ia0 = mbase + w * 16 + (l >> 3);
    int ia1 = ia0 + 8;
    int ra0 = tl[ia0 < n ? ia0 : n - 1];
    int ra1 = tl[ia1 < n ? ia1 : n - 1];
    const unsigned short* gAr0 = hr + (size_t)ra0 * NH + kbase + swz;
    const unsigned short* gAi0 = hi + (size_t)ra0 * NH + kbase + swz;
    const unsigned short* gAr1 = hr + (size_t)ra1 * NH + kbase + swz;
    const unsigned short* gAi1 = hi + (size_t)ra1 * NH + kbase + swz;
    size_t brow = (size_t)e * ND + n0 + w * 16 + (l >> 3);
    const unsigned short* gBr0 = w2tr + brow * NH + kbase + swz;
    const unsigned short* gBr1 = w2tr + (brow + 8) * NH + kbase + swz;
    const unsigned short* gBi0 = w2ti + brow * NH + kbase + swz;
    const unsigned short* gBi1 = w2ti + (brow + 8) * NH + kbase + swz;

    f32x4 accr[4] = {}, acci[4] = {};

    STAGE_(sAr0, sAi0, sBr0, sBi0, 0);
    SYNCPIPE;
    #pragma unroll 1
    for (int kt = 0; kt < (NH / 2) / 64; kt += 2) {
        if (kt + 1 < (NH / 2) / 64) STAGE_(sAr1, sAi1, sBr1, sBi1, (kt + 1) * 64);
        COMPUTE_(sAr0, sAi0, sBr0, sBi0);
        SYNCPIPE;
        if (kt + 2 < (NH / 2) / 64) STAGE_(sAr0, sAi0, sBr0, sBi0, (kt + 2) * 64);
        COMPUTE_(sAr1, sAi1, sBr1, sBi1);
        SYNCPIPE;
    }

    int col = n0 + w * 16 + l15;
    float bre = (ksl == 0) ? b2r[(size_t)e * ND + col] : 0.0f;
    float bie = (ksl == 0) ? b2i[(size_t)e * ND + col] : 0.0f;
    #pragma unroll
    for (int m = 0; m < 4; ++m) {
        #pragma unroll
        for (int r = 0; r < 4; ++r) {
            int tix = m * 16 + quad * 4 + r;
            if (mbase + tix >= n) continue;
            int tok = tl[mbase + tix];
            float gw = gate_w[tok];
            atomicAdd(&out[(size_t)tok * ND + col], (accr[m][r] + bre) * gw);
            atomicAdd(&out[(size_t)NT * ND + (size_t)tok * ND + col], (acci[m][r] + bie) * gw);
        }
    }
}

extern "C" void kernel_launch(void* const* d_in, const int* in_sizes, int n_in,
                              void* d_out, int out_size, void* d_ws, size_t ws_size,
                              hipStream_t stream) {
    const float* xr   = (const float*)d_in[0];
    const float* xi   = (const float*)d_in[1];
    const float* gW   = (const float*)d_in[2];
    const float* gb   = (const float*)d_in[3];
    const float* W1r  = (const float*)d_in[4];
    const float* W1i  = (const float*)d_in[5];
    const float* b1r  = (const float*)d_in[6];
    const float* b1i  = (const float*)d_in[7];
    const float* modb = (const float*)d_in[8];
    const float* W2r  = (const float*)d_in[9];
    const float* W2i  = (const float*)d_in[10];
    const float* b2r  = (const float*)d_in[11];
    const float* b2i  = (const float*)d_in[12];
    float* out = (float*)d_out;

    char* ws = (char*)d_ws;
    int*   counts   = (int*)ws;                              // 256 B
    float* gate_w   = (float*)(ws + 256);                    // NT*4
    int*   tok_list = (int*)(ws + 256 + 8192);               // NE*NT*4
    size_t off = 256 + 8192 + (size_t)NE * NT * 4;
    unsigned short* xbr  = (unsigned short*)(ws + off); off += (size_t)NT * ND * 2;
    unsigned short* xbi  = (unsigned short*)(ws + off); off += (size_t)NT * ND * 2;
    unsigned short* w1tr = (unsigned short*)(ws + off); off += (size_t)NE * ND * NH * 2;
    unsigned short* w1ti = (unsigned short*)(ws + off); off += (size_t)NE * ND * NH * 2;
    unsigned short* w2tr = (unsigned short*)(ws + off); off += (size_t)NE * ND * NH * 2;
    unsigned short* w2ti = (unsigned short*)(ws + off); off += (size_t)NE * ND * NH * 2;
    unsigned short* h_r  = (unsigned short*)(ws + off); off += (size_t)NT * NH * 2;
    unsigned short* h_i  = (unsigned short*)(ws + off); off += (size_t)NT * NH * 2;

    hipMemsetAsync(counts, 0, 64 * sizeof(int), stream);
    hipMemsetAsync(out, 0, (size_t)out_size * sizeof(float), stream);
    gate_kernel<<<NT, 256, 0, stream>>>(xr, xi, gW, gb, gate_w, counts, tok_list);
    convx_kernel<<<(NT * ND / 4) / 256, 256, 0, stream>>>(xr, xi, xbr, xbi);
    transw_kernel<<<dim3(NH / 64, ND / 64, NE), 256, 0, stream>>>(W1r, w1tr, W1i, w1ti, ND, NH);
    transw_kernel<<<dim3(ND / 64, NH / 64, NE), 256, 0, stream>>>(W2r, w2tr, W2i, w2ti, NH, ND);
    moe1_kernel<<<dim3(NH / 64, NT / 64, NE), 256, 0, stream>>>(
        xbr, xbi, w1tr, w1ti, b1r, b1i, modb, counts, tok_list, h_r, h_i);
    moe2_kernel<<<dim3(ND / 64, NT / 64, NE * 2), 256, 0, stream>>>(
        h_r, h_i, w2tr, w2ti, b2r, b2i, counts, tok_list, gate_w, out);
}

// Round 2
// 318.954 us; speedup vs baseline: 1.0138x; 1.0138x over previous
//
#include <hip/hip_runtime.h>
#include <math.h>

#define NE 8      // experts
#define ND 512    // features
#define NH 2048   // hidden
#define NT 2048   // tokens = B*S

typedef __attribute__((ext_vector_type(8))) short short8;   // 8 bf16 = 4 VGPRs
typedef __attribute__((ext_vector_type(4))) float f32x4;    // MFMA accumulator

#define GLL(g, d) __builtin_amdgcn_global_load_lds( \
    (const __attribute__((address_space(1))) void*)(g), \
    (__attribute__((address_space(3))) void*)(d), 16, 0, 0)

__device__ __forceinline__ unsigned short f2bf(float x) {
    unsigned int u = __builtin_bit_cast(unsigned int, x);
    u += 0x7FFFu + ((u >> 16) & 1u);            // round-to-nearest-even
    return (unsigned short)(u >> 16);
}

__device__ __forceinline__ short8 lds8(const unsigned short* p) {
    return *(const short8*)p;
}

// ---------------- gating (fp32, exact argmax semantics) ----------------
__global__ __launch_bounds__(256) void gate_kernel(
    const float* __restrict__ xr, const float* __restrict__ xi,
    const float* __restrict__ gW, const float* __restrict__ gb,
    float* __restrict__ gate_w,
    int* __restrict__ counts, int* __restrict__ tok_list)
{
    int t = blockIdx.x;
    int tid = threadIdx.x;
    const float* xrt = xr + (size_t)t * ND;
    const float* xit = xi + (size_t)t * ND;

    float acc[NE] = {0,0,0,0,0,0,0,0};
    for (int r = tid; r < 2 * ND; r += 256) {
        int d = r & (ND - 1);
        float a = xrt[d], b = xit[d];
        float v = (r < ND) ? sqrtf(a * a + b * b) : atan2f(b, a);
        const float4* g = (const float4*)(gW + (size_t)r * NE);
        float4 g0 = g[0], g1 = g[1];
        acc[0] += v * g0.x; acc[1] += v * g0.y; acc[2] += v * g0.z; acc[3] += v * g0.w;
        acc[4] += v * g1.x; acc[5] += v * g1.y; acc[6] += v * g1.z; acc[7] += v * g1.w;
    }
    #pragma unroll
    for (int e = 0; e < NE; e++) {
        for (int off = 32; off > 0; off >>= 1)
            acc[e] += __shfl_down(acc[e], off, 64);
    }
    __shared__ float part[4][NE];
    int wave = tid >> 6, lane = tid & 63;
    if (lane == 0) {
        #pragma unroll
        for (int e = 0; e < NE; e++) part[wave][e] = acc[e];
    }
    __syncthreads();
    if (tid == 0) {
        float s[NE];
        #pragma unroll
        for (int e = 0; e < NE; e++)
            s[e] = part[0][e] + part[1][e] + part[2][e] + part[3][e] + gb[e];
        int amax = 0; float m = s[0];
        #pragma unroll
        for (int e = 1; e < NE; e++) if (s[e] > m) { m = s[e]; amax = e; }
        float denom = 0.f;
        #pragma unroll
        for (int e = 0; e < NE; e++) denom += expf(s[e] - m);
        gate_w[t] = 1.0f / denom;
        int pos = atomicAdd(&counts[amax], 1);
        tok_list[amax * NT + pos] = t;
    }
}

// ---------------- x -> bf16 ----------------
__global__ __launch_bounds__(256) void convx_kernel(
    const float* __restrict__ xr, const float* __restrict__ xi,
    unsigned short* __restrict__ obr, unsigned short* __restrict__ obi)
{
    int i = blockIdx.x * 256 + threadIdx.x;
    float4 vr = ((const float4*)xr)[i];
    float4 vi = ((const float4*)xi)[i];
    ((ushort4*)obr)[i] = make_ushort4(f2bf(vr.x), f2bf(vr.y), f2bf(vr.z), f2bf(vr.w));
    ((ushort4*)obi)[i] = make_ushort4(f2bf(vi.x), f2bf(vi.y), f2bf(vi.z), f2bf(vi.w));
}

// ---------------- weight transpose + bf16: src fp32 [e][R][C] -> dst bf16 [e][C][R] ----
__global__ __launch_bounds__(256) void transw_kernel(
    const float* __restrict__ s0, unsigned short* __restrict__ d0,
    const float* __restrict__ s1, unsigned short* __restrict__ d1,
    int R, int C)
{
    __shared__ float tile[64][65];
    int e = blockIdx.z;
    int c0 = blockIdx.x * 64, r0 = blockIdx.y * 64;
    size_t off = (size_t)e * R * C;
    int tid = threadIdx.x;
    #pragma unroll
    for (int p = 0; p < 2; ++p) {
        const float* src = (p ? s1 : s0) + off;
        unsigned short* dst = (p ? d1 : d0) + off;
        if (p) __syncthreads();
        for (int i = 0; i < 16; ++i) {
            int idx = tid + i * 256;
            int r = idx >> 6, c = idx & 63;
            tile[r][c] = src[(size_t)(r0 + r) * C + c0 + c];
        }
        __syncthreads();
        #pragma unroll
        for (int i = 0; i < 4; ++i) {
            int c = i * 16 + (tid >> 4);
            int r4 = (tid & 15) * 4;
            ushort4 v = make_ushort4(f2bf(tile[r4][c]), f2bf(tile[r4 + 1][c]),
                                     f2bf(tile[r4 + 2][c]), f2bf(tile[r4 + 3][c]));
            *(ushort4*)&dst[(size_t)(c0 + c) * R + r0 + r4] = v;
        }
    }
}

// ---------------- shared GEMM machinery for moe1/moe2 ----------------
// Double-buffered LDS (8 x 8KB = 64KB), counted-vmcnt pipeline (T3+T4):
//   loop: STAGE(next) -> vmcnt(8) [waits ONLY current tile's 8 loads; next
//         tile's 8 stay in flight across both barriers and compute]
//         -> barrier -> COMPUTE(cur) -> barrier [protects buffer overwrite]
// Prologue drains vmcnt(0) once so older scalar/tok loads never pollute the count.
// LDS XOR swizzle: physical k-chunk = logical ^ (row & 7), applied on the
// global-source side of GLL (LDS slot order fixed to lane order).

#define STAGE_(SA_R, SA_I, SB_R, SB_I, ko) do {  \
    GLL(gAr0 + (ko), SA_R + (w * 16) * 64);      \
    GLL(gAi0 + (ko), SA_I + (w * 16) * 64);      \
    GLL(gAr1 + (ko), SA_R + (w * 16 + 8) * 64);  \
    GLL(gAi1 + (ko), SA_I + (w * 16 + 8) * 64);  \
    GLL(gBr0 + (ko), SB_R + (w * 16) * 64);      \
    GLL(gBr1 + (ko), SB_R + (w * 16 + 8) * 64);  \
    GLL(gBi0 + (ko), SB_I + (w * 16) * 64);      \
    GLL(gBi1 + (ko), SB_I + (w * 16 + 8) * 64);  \
} while (0)

// 4 independent accumulators (RR, II, RI, IR): no neg8 VALU in the hot loop,
// 16 independent MFMA dep chains. Combined in epilogue: r = RR-II, i = RI+IR.
#define COMPUTE_(SA_R, SA_I, SB_R, SB_I) do {                                          \
    _Pragma("unroll")                                                                  \
    for (int ks = 0; ks < 2; ++ks) {                                                   \
        int pa = ((ks * 4 + quad) ^ (l15 & 7)) * 8;                                    \
        short8 br  = lds8(SB_R + (w * 16 + l15) * 64 + pa);                            \
        short8 bi2 = lds8(SB_I + (w * 16 + l15) * 64 + pa);                            \
        _Pragma("unroll")                                                              \
        for (int m = 0; m < 4; ++m) {                                                  \
            short8 ar  = lds8(SA_R + (m * 16 + l15) * 64 + pa);                        \
            short8 ai2 = lds8(SA_I + (m * 16 + l15) * 64 + pa);                        \
            aRR[m] = __builtin_amdgcn_mfma_f32_16x16x32_bf16(ar,  br,  aRR[m], 0, 0, 0); \
            aII[m] = __builtin_amdgcn_mfma_f32_16x16x32_bf16(ai2, bi2, aII[m], 0, 0, 0); \
            aRI[m] = __builtin_amdgcn_mfma_f32_16x16x32_bf16(ar,  bi2, aRI[m], 0, 0, 0); \
            aIR[m] = __builtin_amdgcn_mfma_f32_16x16x32_bf16(ai2, br,  aIR[m], 0, 0, 0); \
        }                                                                              \
    }                                                                                  \
} while (0)

#define VMW8  asm volatile("s_waitcnt vmcnt(8)" ::: "memory")
#define VMW0  asm volatile("s_waitcnt vmcnt(0)" ::: "memory")
#define BARX do {                            \
    __builtin_amdgcn_sched_barrier(0);       \
    __builtin_amdgcn_s_barrier();            \
    __builtin_amdgcn_sched_barrier(0);       \
} while (0)

#define MOE_LDS_DECL                                                        \
    __shared__ alignas(16) unsigned short sAr0[4096], sAi0[4096];           \
    __shared__ alignas(16) unsigned short sBr0[4096], sBi0[4096];           \
    __shared__ alignas(16) unsigned short sAr1[4096], sAi1[4096];           \
    __shared__ alignas(16) unsigned short sBr1[4096], sBi1[4096];

#define PIPE_LOOP(NK) do {                                                  \
    STAGE_(sAr0, sAi0, sBr0, sBi0, 0);                                      \
    VMW0; BARX;                                                             \
    _Pragma("unroll 1")                                                     \
    for (int kt = 0; kt < (NK); kt += 2) {                                  \
        if (kt + 1 < (NK)) { STAGE_(sAr1, sAi1, sBr1, sBi1, (kt + 1) * 64); VMW8; } \
        else VMW0;                                                          \
        BARX;                                                               \
        COMPUTE_(sAr0, sAi0, sBr0, sBi0);                                   \
        BARX;                                                               \
        if (kt + 2 < (NK)) { STAGE_(sAr0, sAi0, sBr0, sBi0, (kt + 2) * 64); VMW8; } \
        else VMW0;                                                          \
        BARX;                                                               \
        COMPUTE_(sAr1, sAi1, sBr1, sBi1);                                   \
        BARX;                                                               \
    }                                                                       \
} while (0)

// ---------------- stage 1: complex D->H, pipelined MFMA + ModReLU -> h bf16 ---
__global__ __launch_bounds__(256, 2) void moe1_kernel(
    const unsigned short* __restrict__ xbr, const unsigned short* __restrict__ xbi,
    const unsigned short* __restrict__ w1tr, const unsigned short* __restrict__ w1ti,
    const float* __restrict__ b1r, const float* __restrict__ b1i,
    const float* __restrict__ mod_b,
    const int* __restrict__ counts, const int* __restrict__ tok_list,
    unsigned short* __restrict__ hr, unsigned short* __restrict__ hi)
{
    int e = blockIdx.z;
    int n = counts[e];
    int mbase = blockIdx.y * 64;
    if (mbase >= n) return;
    int n0 = blockIdx.x * 64;
    int tid = threadIdx.x;
    int w = tid >> 6, l = tid & 63;
    int l15 = l & 15, quad = l >> 4;

    MOE_LDS_DECL

    const int* tl = tok_list + e * NT;
    int swz = (((l & 7) ^ ((l >> 3) & 7)) * 8);
    int ia0 = mbase + w * 16 + (l >> 3);
    int ia1 = ia0 + 8;
    int ra0 = tl[ia0 < n ? ia0 : n - 1];
    int ra1 = tl[ia1 < n ? ia1 : n - 1];
    const unsigned short* gAr0 = xbr + (size_t)ra0 * ND + swz;
    const unsigned short* gAi0 = xbi + (size_t)ra0 * ND + swz;
    const unsigned short* gAr1 = xbr + (size_t)ra1 * ND + swz;
    const unsigned short* gAi1 = xbi + (size_t)ra1 * ND + swz;
    size_t brow = (size_t)e * NH + n0 + w * 16 + (l >> 3);
    const unsigned short* gBr0 = w1tr + brow * ND + swz;
    const unsigned short* gBr1 = w1tr + (brow + 8) * ND + swz;
    const unsigned short* gBi0 = w1ti + brow * ND + swz;
    const unsigned short* gBi1 = w1ti + (brow + 8) * ND + swz;

    f32x4 aRR[4] = {}, aII[4] = {}, aRI[4] = {}, aIR[4] = {};

    PIPE_LOOP(ND / 64);

    // epilogue: C/D layout col = lane&15 (N), row = quad*4 + r (M)
    int col = n0 + w * 16 + l15;
    float bre = b1r[(size_t)e * NH + col];
    float bie = b1i[(size_t)e * NH + col];
    float mbv = mod_b[(size_t)e * NH + col];
    #pragma unroll
    for (int m = 0; m < 4; ++m) {
        #pragma unroll
        for (int r = 0; r < 4; ++r) {
            int tix = m * 16 + quad * 4 + r;
            if (mbase + tix >= n) continue;
            int tok = tl[mbase + tix];
            float vr = aRR[m][r] - aII[m][r] + bre;
            float vi = aRI[m][r] + aIR[m][r] + bie;
            float a = sqrtf(vr * vr + vi * vi + 1e-10f);
            float sc = fmaxf(a + mbv, 0.0f) / (a + 1e-10f);
            hr[(size_t)tok * NH + col] = f2bf(vr * sc);
            hi[(size_t)tok * NH + col] = f2bf(vi * sc);
        }
    }
}

// ---------------- stage 2: complex H->D, split-K=2, pipelined MFMA -> atomic out
__global__ __launch_bounds__(256, 2) void moe2_kernel(
    const unsigned short* __restrict__ hr, const unsigned short* __restrict__ hi,
    const unsigned short* __restrict__ w2tr, const unsigned short* __restrict__ w2ti,
    const float* __restrict__ b2r, const float* __restrict__ b2i,
    const int* __restrict__ counts, const int* __restrict__ tok_list,
    const float* __restrict__ gate_w,
    float* __restrict__ out)
{
    int e = blockIdx.z >> 1;
    int ksl = blockIdx.z & 1;
    int n = counts[e];
    int mbase = blockIdx.y * 64;
    if (mbase >= n) return;
    int n0 = blockIdx.x * 64;
    int kbase = ksl * (NH / 2);
    int tid = threadIdx.x;
    int w = tid >> 6, l = tid & 63;
    int l15 = l & 15, quad = l >> 4;

    MOE_LDS_DECL

    const int* tl = tok_list + e * NT;
    int swz = (((l & 7) ^ ((l >> 3) & 7)) * 8);
    int ia0 = mbase + w * 16 + (l >> 3);
    int ia1 = ia0 + 8;
    int ra0 = tl[ia0 < n ? ia0 : n - 1];
    int ra1 = tl[ia1 < n ? ia1 : n - 1];
    const unsigned short* gAr0 = hr + (size_t)ra0 * NH + kbase + swz;
    const unsigned short* gAi0 = hi + (size_t)ra0 * NH + kbase + swz;
    const unsigned short* gAr1 = hr + (size_t)ra1 * NH + kbase + swz;
    const unsigned short* gAi1 = hi + (size_t)ra1 * NH + kbase + swz;
    size_t brow = (size_t)e * ND + n0 + w * 16 + (l >> 3);
    const unsigned short* gBr0 = w2tr + brow * NH + kbase + swz;
    const unsigned short* gBr1 = w2tr + (brow + 8) * NH + kbase + swz;
    const unsigned short* gBi0 = w2ti + brow * NH + kbase + swz;
    const unsigned short* gBi1 = w2ti + (brow + 8) * NH + kbase + swz;

    f32x4 aRR[4] = {}, aII[4] = {}, aRI[4] = {}, aIR[4] = {};

    PIPE_LOOP((NH / 2) / 64);

    int col = n0 + w * 16 + l15;
    float bre = (ksl == 0) ? b2r[(size_t)e * ND + col] : 0.0f;
    float bie = (ksl == 0) ? b2i[(size_t)e * ND + col] : 0.0f;
    #pragma unroll
    for (int m = 0; m < 4; ++m) {
        #pragma unroll
        for (int r = 0; r < 4; ++r) {
            int tix = m * 16 + quad * 4 + r;
            if (mbase + tix >= n) continue;
            int tok = tl[mbase + tix];
            float gw = gate_w[tok];
            atomicAdd(&out[(size_t)tok * ND + col], (aRR[m][r] - aII[m][r] + bre) * gw);
            atomicAdd(&out[(size_t)NT * ND + (size_t)tok * ND + col], (aRI[m][r] + aIR[m][r] + bie) * gw);
        }
    }
}

extern "C" void kernel_launch(void* const* d_in, const int* in_sizes, int n_in,
                              void* d_out, int out_size, void* d_ws, size_t ws_size,
                              hipStream_t stream) {
    const float* xr   = (const float*)d_in[0];
    const float* xi   = (const float*)d_in[1];
    const float* gW   = (const float*)d_in[2];
    const float* gb   = (const float*)d_in[3];
    const float* W1r  = (const float*)d_in[4];
    const float* W1i  = (const float*)d_in[5];
    const float* b1r  = (const float*)d_in[6];
    const float* b1i  = (const float*)d_in[7];
    const float* modb = (const float*)d_in[8];
    const float* W2r  = (const float*)d_in[9];
    const float* W2i  = (const float*)d_in[10];
    const float* b2r  = (const float*)d_in[11];
    const float* b2i  = (const float*)d_in[12];
    float* out = (float*)d_out;

    char* ws = (char*)d_ws;
    int*   counts   = (int*)ws;                              // 256 B
    float* gate_w   = (float*)(ws + 256);                    // NT*4
    int*   tok_list = (int*)(ws + 256 + 8192);               // NE*NT*4
    size_t off = 256 + 8192 + (size_t)NE * NT * 4;
    unsigned short* xbr  = (unsigned short*)(ws + off); off += (size_t)NT * ND * 2;
    unsigned short* xbi  = (unsigned short*)(ws + off); off += (size_t)NT * ND * 2;
    unsigned short* w1tr = (unsigned short*)(ws + off); off += (size_t)NE * ND * NH * 2;
    unsigned short* w1ti = (unsigned short*)(ws + off); off += (size_t)NE * ND * NH * 2;
    unsigned short* w2tr = (unsigned short*)(ws + off); off += (size_t)NE * ND * NH * 2;
    unsigned short* w2ti = (unsigned short*)(ws + off); off += (size_t)NE * ND * NH * 2;
    unsigned short* h_r  = (unsigned short*)(ws + off); off += (size_t)NT * NH * 2;
    unsigned short* h_i  = (unsigned short*)(ws + off); off += (size_t)NT * NH * 2;

    hipMemsetAsync(counts, 0, 64 * sizeof(int), stream);
    hipMemsetAsync(out, 0, (size_t)out_size * sizeof(float), stream);
    gate_kernel<<<NT, 256, 0, stream>>>(xr, xi, gW, gb, gate_w, counts, tok_list);
    convx_kernel<<<(NT * ND / 4) / 256, 256, 0, stream>>>(xr, xi, xbr, xbi);
    transw_kernel<<<dim3(NH / 64, ND / 64, NE), 256, 0, stream>>>(W1r, w1tr, W1i, w1ti, ND, NH);
    transw_kernel<<<dim3(ND / 64, NH / 64, NE), 256, 0, stream>>>(W2r, w2tr, W2i, w2ti, NH, ND);
    moe1_kernel<<<dim3(NH / 64, NT / 64, NE), 256, 0, stream>>>(
        xbr, xbi, w1tr, w1ti, b1r, b1i, modb, counts, tok_list, h_r, h_i);
    moe2_kernel<<<dim3(ND / 64, NT / 64, NE * 2), 256, 0, stream>>>(
        h_r, h_i, w2tr, w2ti, b2r, b2i, counts, tok_list, gate_w, out);
}